// Round 1
// baseline (8144.503 us; speedup 1.0000x reference)
//
#include <hip/hip_runtime.h>

#define N_USER 100000
#define N_ITEM 50000
#define N_NODES 150000
#define DIM 64
#define N_NNZ 6400000
#define N_LAYER 3

// One wave (64 lanes) per edge. lane = dim index (DIM == wavefront size).
// Reads source row (coalesced 256B), scales by val, atomic-adds into dest row.
// Does both directions: user <- adj @ item, item <- adj^T @ user.
__global__ __launch_bounds__(256) void scatter_kernel(
    const int* __restrict__ rows,
    const int* __restrict__ cols,
    const float* __restrict__ vals,
    const float* __restrict__ lat_prev,
    float* __restrict__ gcn_out)
{
    const int gtid = blockIdx.x * blockDim.x + threadIdx.x;
    const int edge = gtid >> 6;
    const int lane = gtid & 63;
    if (edge >= N_NNZ) return;

    const int r = rows[edge];          // user index  [0, N_USER)
    const int c = cols[edge];          // item index  [0, N_ITEM)
    const float v = vals[edge];

    // user_embeds[r] += v * item_part[c]
    const float item_val = lat_prev[(size_t)(N_USER + c) * DIM + lane];
    atomicAdd(&gcn_out[(size_t)r * DIM + lane], v * item_val);

    // item_embeds[c] += v * user_part[r]
    const float user_val = lat_prev[(size_t)r * DIM + lane];
    atomicAdd(&gcn_out[(size_t)(N_USER + c) * DIM + lane], v * user_val);
}

// lats[l] = lats[l-1] + gcn[l], vectorized float4
__global__ __launch_bounds__(256) void residual_add_kernel(
    const float4* __restrict__ a,
    const float4* __restrict__ b,
    float4* __restrict__ out,
    int n4)
{
    int i = blockIdx.x * blockDim.x + threadIdx.x;
    if (i < n4) {
        float4 av = a[i], bv = b[i];
        out[i] = make_float4(av.x + bv.x, av.y + bv.y, av.z + bv.z, av.w + bv.w);
    }
}

extern "C" void kernel_launch(void* const* d_in, const int* in_sizes, int n_in,
                              void* d_out, int out_size, void* d_ws, size_t ws_size,
                              hipStream_t stream) {
    const int*   rows   = (const int*)d_in[0];
    const int*   cols   = (const int*)d_in[1];
    const float* vals   = (const float*)d_in[2];
    const float* embeds = (const float*)d_in[3];

    float* out = (float*)d_out;
    const size_t N = (size_t)N_NODES * DIM;   // 9,600,000 floats per snapshot

    float* lats = out;            // [4][N_NODES][DIM]
    float* gcn  = out + 4 * N;    // [4][N_NODES][DIM]

    // lats[0] = embeds; gcn[0] = embeds
    hipMemcpyAsync(lats, embeds, N * sizeof(float), hipMemcpyDeviceToDevice, stream);
    hipMemcpyAsync(gcn,  embeds, N * sizeof(float), hipMemcpyDeviceToDevice, stream);
    // gcn[1..3] = 0 (scatter accumulates into these; d_out arrives poisoned)
    hipMemsetAsync(gcn + N, 0, 3 * N * sizeof(float), stream);

    const int scatter_threads = 256;
    const int scatter_blocks  = (N_NNZ * 64 + scatter_threads - 1) / scatter_threads;
    const int n4 = (int)(N / 4);
    const int add_blocks = (n4 + 255) / 256;

    for (int l = 1; l <= N_LAYER; ++l) {
        const float* lat_prev = lats + (size_t)(l - 1) * N;
        float*       gcn_l    = gcn  + (size_t)l * N;
        float*       lat_l    = lats + (size_t)l * N;

        scatter_kernel<<<scatter_blocks, scatter_threads, 0, stream>>>(
            rows, cols, vals, lat_prev, gcn_l);

        residual_add_kernel<<<add_blocks, 256, 0, stream>>>(
            (const float4*)lat_prev, (const float4*)gcn_l, (float4*)lat_l, n4);
    }
}

// Round 2
// 3300.504 us; speedup vs baseline: 2.4677x; 2.4677x over previous
//
#include <hip/hip_runtime.h>

#define N_USER 100000
#define N_ITEM 50000
#define N_NODES 150000
#define DIM 64
#define N_NNZ 6400000
#define N_LAYER 3
#define TOTAL_EDGES (2 * N_NNZ)   // each nnz contributes to one user row and one item row

// ---------------------------------------------------------------------------
// CSR build: histogram -> exclusive scan -> cursor fill
// ---------------------------------------------------------------------------

__global__ __launch_bounds__(256) void histogram_kernel(
    const int* __restrict__ rows,
    const int* __restrict__ cols,
    int* __restrict__ counts)   // [N_NODES + 1], pre-zeroed
{
    int e = blockIdx.x * blockDim.x + threadIdx.x;
    if (e >= N_NNZ) return;
    atomicAdd(&counts[rows[e]], 1);
    atomicAdd(&counts[N_USER + cols[e]], 1);
}

// Single-block exclusive scan in place. 1024 threads = 16 waves.
// Wave-level shfl scan + per-chunk carry: 3 barriers per 1024-element chunk.
__global__ __launch_bounds__(1024) void scan_kernel(int* __restrict__ data, int n)
{
    __shared__ int wsum[16];
    __shared__ int woff[16];
    __shared__ int carry_s;
    if (threadIdx.x == 0) carry_s = 0;
    __syncthreads();

    const int lane = threadIdx.x & 63;
    const int wid  = threadIdx.x >> 6;

    for (int base = 0; base < n; base += 1024) {
        int i = base + (int)threadIdx.x;
        int v = (i < n) ? data[i] : 0;

        // wave-inclusive scan
        int incl = v;
        #pragma unroll
        for (int off = 1; off < 64; off <<= 1) {
            int t = __shfl_up(incl, off, 64);
            if (lane >= off) incl += t;
        }
        if (lane == 63) wsum[wid] = incl;
        __syncthreads();

        if (threadIdx.x == 0) {
            int s = carry_s;
            #pragma unroll
            for (int w = 0; w < 16; ++w) { woff[w] = s; s += wsum[w]; }
            carry_s = s;
        }
        __syncthreads();

        if (i < n) data[i] = woff[wid] + incl - v;   // exclusive
        __syncthreads();   // protect wsum/carry_s for next chunk
    }
}

__global__ __launch_bounds__(256) void fill_kernel(
    const int* __restrict__ rows,
    const int* __restrict__ cols,
    const float* __restrict__ vals,
    int* __restrict__ cursor,      // copy of offsets, advanced atomically
    int2* __restrict__ edges)      // [TOTAL_EDGES] packed (src_node, val_bits)
{
    int e = blockIdx.x * blockDim.x + threadIdx.x;
    if (e >= N_NNZ) return;
    const int r = rows[e];
    const int c = cols[e];
    const int vb = __float_as_int(vals[e]);
    // user row r gathers from item node (N_USER + c)
    int pu = atomicAdd(&cursor[r], 1);
    edges[pu] = make_int2(N_USER + c, vb);
    // item row (N_USER + c) gathers from user node r
    int pi = atomicAdd(&cursor[N_USER + c], 1);
    edges[pi] = make_int2(r, vb);
}

// ---------------------------------------------------------------------------
// Gather propagation: one wave per output row, lane = dim. Fused residual.
// ---------------------------------------------------------------------------
__global__ __launch_bounds__(256) void gather_kernel(
    const int* __restrict__ offsets,
    const int2* __restrict__ edges,
    const float* __restrict__ lat_prev,
    float* __restrict__ gcn_l,
    float* __restrict__ lat_l)
{
    const int gtid = blockIdx.x * blockDim.x + threadIdx.x;
    const int node = gtid >> 6;
    const int lane = gtid & 63;
    if (node >= N_NODES) return;

    const int beg = offsets[node];
    const int end = offsets[node + 1];

    float acc = 0.f;
    int e = beg;
    for (; e + 4 <= end; e += 4) {
        int2 e0 = edges[e];
        int2 e1 = edges[e + 1];
        int2 e2 = edges[e + 2];
        int2 e3 = edges[e + 3];
        float x0 = lat_prev[(size_t)e0.x * DIM + lane];
        float x1 = lat_prev[(size_t)e1.x * DIM + lane];
        float x2 = lat_prev[(size_t)e2.x * DIM + lane];
        float x3 = lat_prev[(size_t)e3.x * DIM + lane];
        acc += __int_as_float(e0.y) * x0;
        acc += __int_as_float(e1.y) * x1;
        acc += __int_as_float(e2.y) * x2;
        acc += __int_as_float(e3.y) * x3;
    }
    for (; e < end; ++e) {
        int2 ee = edges[e];
        acc += __int_as_float(ee.y) * lat_prev[(size_t)ee.x * DIM + lane];
    }

    const size_t o = (size_t)node * DIM + lane;
    gcn_l[o] = acc;
    lat_l[o] = lat_prev[o] + acc;
}

// ---------------------------------------------------------------------------
// Fallback (atomic scatter) if workspace is too small
// ---------------------------------------------------------------------------
__global__ __launch_bounds__(256) void scatter_kernel(
    const int* __restrict__ rows,
    const int* __restrict__ cols,
    const float* __restrict__ vals,
    const float* __restrict__ lat_prev,
    float* __restrict__ gcn_out)
{
    const int gtid = blockIdx.x * blockDim.x + threadIdx.x;
    const int edge = gtid >> 6;
    const int lane = gtid & 63;
    if (edge >= N_NNZ) return;
    const int r = rows[edge];
    const int c = cols[edge];
    const float v = vals[edge];
    atomicAdd(&gcn_out[(size_t)r * DIM + lane],
              v * lat_prev[(size_t)(N_USER + c) * DIM + lane]);
    atomicAdd(&gcn_out[(size_t)(N_USER + c) * DIM + lane],
              v * lat_prev[(size_t)r * DIM + lane]);
}

__global__ __launch_bounds__(256) void residual_add_kernel(
    const float4* __restrict__ a,
    const float4* __restrict__ b,
    float4* __restrict__ out,
    int n4)
{
    int i = blockIdx.x * blockDim.x + threadIdx.x;
    if (i < n4) {
        float4 av = a[i], bv = b[i];
        out[i] = make_float4(av.x + bv.x, av.y + bv.y, av.z + bv.z, av.w + bv.w);
    }
}

extern "C" void kernel_launch(void* const* d_in, const int* in_sizes, int n_in,
                              void* d_out, int out_size, void* d_ws, size_t ws_size,
                              hipStream_t stream) {
    const int*   rows   = (const int*)d_in[0];
    const int*   cols   = (const int*)d_in[1];
    const float* vals   = (const float*)d_in[2];
    const float* embeds = (const float*)d_in[3];

    float* out = (float*)d_out;
    const size_t N = (size_t)N_NODES * DIM;   // floats per snapshot

    float* lats = out;            // [4][N_NODES][DIM]
    float* gcn  = out + 4 * N;    // [4][N_NODES][DIM]

    // lats[0] = gcn[0] = embeds
    hipMemcpyAsync(lats, embeds, N * sizeof(float), hipMemcpyDeviceToDevice, stream);
    hipMemcpyAsync(gcn,  embeds, N * sizeof(float), hipMemcpyDeviceToDevice, stream);

    // Workspace layout
    const size_t off_bytes    = (size_t)(N_NODES + 1) * sizeof(int);          // 600,004
    const size_t cursor_off   = (off_bytes + 15) & ~(size_t)15;               // 600,016
    const size_t cursor_bytes = (size_t)N_NODES * sizeof(int);                // 600,000
    const size_t edges_off    = (cursor_off + cursor_bytes + 15) & ~(size_t)15;
    const size_t edges_bytes  = (size_t)TOTAL_EDGES * sizeof(int2);           // 102,400,000
    const size_t need = edges_off + edges_bytes;

    if (ws_size >= need) {
        int*  offsets = (int*)d_ws;
        int*  cursor  = (int*)((char*)d_ws + cursor_off);
        int2* edges   = (int2*)((char*)d_ws + edges_off);

        // Build CSR (must run every call: ws is re-poisoned)
        hipMemsetAsync(offsets, 0, off_bytes, stream);
        const int eb = (N_NNZ + 255) / 256;
        histogram_kernel<<<eb, 256, 0, stream>>>(rows, cols, offsets);
        scan_kernel<<<1, 1024, 0, stream>>>(offsets, N_NODES + 1);
        hipMemcpyAsync(cursor, offsets, cursor_bytes, hipMemcpyDeviceToDevice, stream);
        fill_kernel<<<eb, 256, 0, stream>>>(rows, cols, vals, cursor, edges);

        // Propagate
        const int gb = (N_NODES * 64 + 255) / 256;
        for (int l = 1; l <= N_LAYER; ++l) {
            const float* lat_prev = lats + (size_t)(l - 1) * N;
            gather_kernel<<<gb, 256, 0, stream>>>(
                offsets, edges, lat_prev,
                gcn  + (size_t)l * N,
                lats + (size_t)l * N);
        }
    } else {
        // Fallback: atomic scatter (round-1 path)
        hipMemsetAsync(gcn + N, 0, 3 * N * sizeof(float), stream);
        const int scatter_blocks = (N_NNZ * 64 + 255) / 256;
        const int n4 = (int)(N / 4);
        const int add_blocks = (n4 + 255) / 256;
        for (int l = 1; l <= N_LAYER; ++l) {
            const float* lat_prev = lats + (size_t)(l - 1) * N;
            float* gcn_l = gcn  + (size_t)l * N;
            float* lat_l = lats + (size_t)l * N;
            scatter_kernel<<<scatter_blocks, 256, 0, stream>>>(
                rows, cols, vals, lat_prev, gcn_l);
            residual_add_kernel<<<add_blocks, 256, 0, stream>>>(
                (const float4*)lat_prev, (const float4*)gcn_l, (float4*)lat_l, n4);
        }
    }
}